// Round 16
// baseline (254.535 us; speedup 1.0000x reference)
//
#include <hip/hip_runtime.h>
#include <hip/hip_bf16.h>

typedef unsigned short u16;
typedef unsigned int u32;
typedef float f32x4 __attribute__((ext_vector_type(4)));
typedef float f32x16 __attribute__((ext_vector_type(16)));
typedef __bf16 bf16x8 __attribute__((ext_vector_type(8)));
typedef u32 u32x2 __attribute__((ext_vector_type(2)));

#define DEV static __device__ __forceinline__

DEV u16 f2b(float f) { __bf16 h = (__bf16)f; u16 r; __builtin_memcpy(&r, &h, 2); return r; }
DEV u32 pk2(float a, float b) { return (u32)f2b(a) | ((u32)f2b(b) << 16); }
DEV bf16x8 as_bf(uint4 v) { bf16x8 r; __builtin_memcpy(&r, &v, 16); return r; }

#define GLDS(g, l) __builtin_amdgcn_global_load_lds( \
    (__attribute__((address_space(1))) void*)(g),     \
    (__attribute__((address_space(3))) void*)(l), 16, 0, 0)

// counted-vmcnt barriers -- PURE global_load_lds streams only.
DEV void wb4() { asm volatile("s_waitcnt vmcnt(4)\n\ts_barrier" ::: "memory"); }
DEV void wb0() { asm volatile("s_waitcnt vmcnt(0)\n\ts_barrier" ::: "memory"); }

// ---------------------------------------------------------------------------
// All fp32->bf16 conversions in one launch. grid (2048, 4):
// y in {0,1,2}: query/key/value (1M x 8 elems, grid-stride x2)
// y == 3: the 4 weight matrices (512K x 8 elems, exactly 1/thread)
// ---------------------------------------------------------------------------
__global__ __launch_bounds__(256) void conv_all(const float* __restrict__ q,
                                                const float* __restrict__ k,
                                                const float* __restrict__ v,
                                                const float* __restrict__ w0,
                                                const float* __restrict__ w1,
                                                const float* __restrict__ w2,
                                                const float* __restrict__ w3,
                                                u16* __restrict__ Ac3,
                                                u16* __restrict__ Wc)
{
  const int y = blockIdx.y;
  if (y < 3) {
    const float* s = y == 0 ? q : (y == 1 ? k : v);
    u16* d = Ac3 + (size_t)y * 8388608;
    const int stride = gridDim.x * 256;
    for (int i = blockIdx.x * 256 + threadIdx.x; i < 1048576; i += stride) {
      const float4* p = (const float4*)(s + (size_t)i * 8);
      const float4 a = p[0], b = p[1];
      *(uint4*)(d + (size_t)i * 8) =
          make_uint4(pk2(a.x, a.y), pk2(a.z, a.w), pk2(b.x, b.y), pk2(b.z, b.w));
    }
  } else {
    const int i = blockIdx.x * 256 + threadIdx.x;     // [0, 524288)
    const int seg = i >> 17, off = i & 131071;
    const float* s = seg == 0 ? w0 : seg == 1 ? w1 : seg == 2 ? w2 : w3;
    const float4* p = (const float4*)(s + (size_t)off * 8);
    const float4 a = p[0], b = p[1];
    *(uint4*)(Wc + (size_t)seg * 1048576 + (size_t)off * 8) =
        make_uint4(pk2(a.x, a.y), pk2(a.z, a.w), pk2(b.x, b.y), pk2(b.z, b.w));
  }
}

// ---------------------------------------------------------------------------
// Fused QKV projection GEMM, z-MAJOR block order: f = z*512 + (m + 64*e).
// Dispatch runs z=0's 512 blocks first, replicating round-7's per-matrix
// locality exactly (A-tile's 8 e-blocks all id=m mod 8 -> same XCD -> A-tile
// L2-hit x8; one z's B (2MB) per XCD at a time), minus 2 launch boundaries.
// 128x128 tile, BK=32, 4 waves 64x64, ring-3 + counted vmcnt(4) (proven).
// ---------------------------------------------------------------------------
__global__ __launch_bounds__(256) void gemm_qkv(const u16* __restrict__ Ac,
                                                const u16* __restrict__ Wc,
                                                const float* __restrict__ b0,
                                                const float* __restrict__ b1,
                                                const float* __restrict__ b2,
                                                u16* __restrict__ C0,
                                                u16* __restrict__ C1,
                                                u16* __restrict__ C2,
                                                float qscale)
{
  __shared__ u16 lds[3][8192];                 // ring slot: [A 4096 | B 4096]
  const int tid = threadIdx.x;
  const int lane = tid & 63, w = tid >> 6;
  const int f = blockIdx.x;
  const int z = f >> 9, r = f & 511;
  const int m0 = (r & 63) * 128, e0 = (r >> 6) * 128;
  const int wrb = (w >> 1) * 4, wcb = (w & 1) * 4;

  const u16* A = Ac + (size_t)z * 8388608;
  const u16* Wp = Wc + (size_t)z * 1048576;
  const float* bias = z == 0 ? b0 : (z == 1 ? b1 : b2);
  u16* Cp = z == 0 ? C0 : (z == 1 ? C1 : C2);
  const float scale = (z == 0) ? qscale : 1.0f;
  const int cmode = (z == 2) ? 3 : 2;

  f32x4 acc[4][4];
#pragma unroll
  for (int ii = 0; ii < 4; ii++)
#pragma unroll
    for (int j = 0; j < 4; j++)
#pragma unroll
      for (int rr = 0; rr < 4; rr++) acc[ii][j][rr] = 0.f;

  const u16* gA = A  + (size_t)(m0 + w * 32 + (lane & 15)) * 1024 + (lane >> 4) * 8;
  const u16* gB = Wp + (size_t)(e0 + w * 32 + (lane & 15)) * 1024 + (lane >> 4) * 8;

#define GSTAGE(K0, BUF)                                        \
  GLDS(gA + (K0),         &lds[BUF][w * 1024]);                \
  GLDS(gA + (K0) + 16384, &lds[BUF][w * 1024 + 512]);          \
  GLDS(gB + (K0),         &lds[BUF][4096 + w * 1024]);         \
  GLDS(gB + (K0) + 16384, &lds[BUF][4096 + w * 1024 + 512]);

  GSTAGE(0, 0)
  GSTAGE(32, 1)

  const int fo = (lane >> 4) * 128 + (lane & 15) * 8;

#define GEMM_STEP(BUF)                                                         \
  {                                                                            \
    const u16* la = &lds[BUF][0];                                              \
    const u16* lb = &lds[BUF][4096];                                           \
    bf16x8 af[4], bfr[4];                                                      \
    _Pragma("unroll")                                                          \
    for (int ii = 0; ii < 4; ii++) {                                           \
      af[ii]  = as_bf(*(const uint4*)(la + (wrb + ii) * 512 + fo));            \
      bfr[ii] = as_bf(*(const uint4*)(lb + (wcb + ii) * 512 + fo));            \
    }                                                                          \
    _Pragma("unroll")                                                          \
    for (int ii = 0; ii < 4; ii++)                                             \
      _Pragma("unroll")                                                        \
      for (int j = 0; j < 4; j++)                                              \
        acc[ii][j] = __builtin_amdgcn_mfma_f32_16x16x32_bf16(af[ii], bfr[j],   \
                                                             acc[ii][j], 0, 0, 0); \
  }

  for (int t = 0; t < 30; t += 3) {
    wb4(); GSTAGE((t + 2) * 32, 2) GEMM_STEP(0)
    wb4(); GSTAGE((t + 3) * 32, 0) GEMM_STEP(1)
    wb4(); GSTAGE((t + 4) * 32, 1) GEMM_STEP(2)
  }
  wb4(); GEMM_STEP(0)
  wb0(); GEMM_STEP(1)
#undef GEMM_STEP
#undef GSTAGE

  const int col = lane & 15, rb4 = (lane >> 4) * 4;
  const int wr = wrb * 16, wc = wcb * 16;
#pragma unroll
  for (int j = 0; j < 4; j++) {
    const int e = e0 + wc + j * 16 + col;
    const float bv2 = bias[e];
#pragma unroll
    for (int ii = 0; ii < 4; ii++) {
#pragma unroll
      for (int rr = 0; rr < 4; rr++) {
        const int m = m0 + wr + ii * 16 + rb4 + rr;
        const float v = (acc[ii][j][rr] + bv2) * scale;
        const int b = m >> 11, s = m & 2047, h = e >> 6, dh = e & 63;
        const size_t bh = (size_t)(b * 16 + h);
        if (cmode == 2) {
          const size_t idx = (((bh * 64 + (s >> 5)) * 4 + (dh >> 4)) * 64
                              + ((dh >> 3) & 1) * 32 + (s & 31)) * 8 + (dh & 7);
          Cp[idx] = f2b(v);
        } else {
          const size_t idx = ((bh * 64 + (s >> 5)) * 8 + ((s >> 4) & 1) * 4
                              + (dh >> 5) * 2 + ((s >> 3) & 1)) * 256
                             + (size_t)(dh & 31) * 8 + (s & 7);
          Cp[idx] = f2b(v);
        }
      }
    }
  }
}

// ---------------------------------------------------------------------------
// Output GEMM (proven): bf16 A/W via GLDS, fp32 out + bias. 128x128, BK=32,
// 4 waves, ring-3 + counted vmcnt(4).
// ---------------------------------------------------------------------------
__global__ __launch_bounds__(256) void gemm_o(const u16* __restrict__ A,
                                              const u16* __restrict__ W,
                                              const float* __restrict__ bias,
                                              float* __restrict__ Cp)
{
  __shared__ u16 lds[3][8192];
  const int tid = threadIdx.x;
  const int lane = tid & 63, w = tid >> 6;
  const int m0 = blockIdx.x * 128, e0 = blockIdx.y * 128;
  const int wrb = (w >> 1) * 4, wcb = (w & 1) * 4;

  f32x4 acc[4][4];
#pragma unroll
  for (int i = 0; i < 4; i++)
#pragma unroll
    for (int j = 0; j < 4; j++)
#pragma unroll
      for (int r = 0; r < 4; r++) acc[i][j][r] = 0.f;

  const u16* gA = A + (size_t)(m0 + w * 32 + (lane & 15)) * 1024 + (lane >> 4) * 8;
  const u16* gB = W + (size_t)(e0 + w * 32 + (lane & 15)) * 1024 + (lane >> 4) * 8;

#define GSTAGE(K0, BUF)                                        \
  GLDS(gA + (K0),         &lds[BUF][w * 1024]);                \
  GLDS(gA + (K0) + 16384, &lds[BUF][w * 1024 + 512]);          \
  GLDS(gB + (K0),         &lds[BUF][4096 + w * 1024]);         \
  GLDS(gB + (K0) + 16384, &lds[BUF][4096 + w * 1024 + 512]);

  GSTAGE(0, 0)
  GSTAGE(32, 1)

  const int fo = (lane >> 4) * 128 + (lane & 15) * 8;

#define GEMM_STEP(BUF)                                                         \
  {                                                                            \
    const u16* la = &lds[BUF][0];                                              \
    const u16* lb = &lds[BUF][4096];                                           \
    bf16x8 af[4], bfr[4];                                                      \
    _Pragma("unroll")                                                          \
    for (int i = 0; i < 4; i++) {                                              \
      af[i]  = as_bf(*(const uint4*)(la + (wrb + i) * 512 + fo));              \
      bfr[i] = as_bf(*(const uint4*)(lb + (wcb + i) * 512 + fo));              \
    }                                                                          \
    _Pragma("unroll")                                                          \
    for (int i = 0; i < 4; i++)                                                \
      _Pragma("unroll")                                                        \
      for (int j = 0; j < 4; j++)                                              \
        acc[i][j] = __builtin_amdgcn_mfma_f32_16x16x32_bf16(af[i], bfr[j],     \
                                                            acc[i][j], 0, 0, 0); \
  }

  for (int t = 0; t < 30; t += 3) {
    wb4(); GSTAGE((t + 2) * 32, 2) GEMM_STEP(0)
    wb4(); GSTAGE((t + 3) * 32, 0) GEMM_STEP(1)
    wb4(); GSTAGE((t + 4) * 32, 1) GEMM_STEP(2)
  }
  wb4(); GEMM_STEP(0)
  wb0(); GEMM_STEP(1)
#undef GEMM_STEP
#undef GSTAGE

  const int col = lane & 15, rb4 = (lane >> 4) * 4;
  const int wr = wrb * 16, wc = wcb * 16;
#pragma unroll
  for (int j = 0; j < 4; j++) {
    const int e = e0 + wc + j * 16 + col;
    const float bv = bias[e];
#pragma unroll
    for (int i = 0; i < 4; i++) {
#pragma unroll
      for (int r = 0; r < 4; r++) {
        const int m = m0 + wr + i * 16 + rb4 + r;
        Cp[(size_t)m * 1024 + e] = acc[i][j][r] + bv;
      }
    }
  }
}

// ---------------------------------------------------------------------------
// Flash attention v9: 2 k-tiles per barrier window. 4 waves x 32 q = 128 q of
// one bh; double-buffered 16KB slots [KA|VA|KB|VB], 32 barriers (was 64), two
// independent QK/softmax/PV chains per window for ILP (diagnosis: latency-
// bound, both pipes <50%). Fixed-shift softmax p=exp2(s); raw v_exp_f32;
// VALU denominator; XCD-grouped bh mapping.
// ---------------------------------------------------------------------------
__global__ __launch_bounds__(256, 4) void attn_k(const u16* __restrict__ Qb,
                                                 const u16* __restrict__ Kb,
                                                 const u16* __restrict__ Vb,
                                                 u16* __restrict__ O)
{
  __shared__ u16 pool[16384];      // dbuf 2 x 8192; epilogue aliases
  const int tid = threadIdx.x, wv = tid >> 6, lane = tid & 63;
  const int lo = lane & 31, hi = lane >> 5;
  const int bid = blockIdx.x;
  const int xcd = bid & 7, ix = bid >> 3;
  const int bh = xcd * 8 + (ix & 7);
  const int qb = (ix >> 3) * 4 + wv;
  const int b = bh >> 4, h = bh & 15, q0 = qb * 32;

  const u16* qp = Qb + ((size_t)(bh * 64 + qb) * 4) * 512 + (size_t)lane * 8;
  bf16x8 qf[4];
#pragma unroll
  for (int c = 0; c < 4; c++) qf[c] = as_bf(*(const uint4*)(qp + c * 512));

  f32x16 a0, a1, zv;
#pragma unroll
  for (int r = 0; r < 16; r++) { a0[r] = 0.f; a1[r] = 0.f; zv[r] = 0.f; }
  float ls0 = 0.f, ls1 = 0.f;

  const u16* sgK = Kb + (size_t)bh * 131072 + wv * 512 + (size_t)lane * 8;
  const u16* sgV = Vb + (size_t)bh * 131072 + wv * 512 + (size_t)lane * 8;

// stage tile-pair T2 (tiles 2*T2, 2*T2+1) into slot BUF
#define ASTAGE2(T2, BUF)                                                       \
  GLDS(sgK + (size_t)(2 * (T2))     * 2048, pool + (BUF) * 8192 +        wv * 512); \
  GLDS(sgV + (size_t)(2 * (T2))     * 2048, pool + (BUF) * 8192 + 2048 + wv * 512); \
  GLDS(sgK + (size_t)(2 * (T2) + 1) * 2048, pool + (BUF) * 8192 + 4096 + wv * 512); \
  GLDS(sgV + (size_t)(2 * (T2) + 1) * 2048, pool + (BUF) * 8192 + 6144 + wv * 512);

#define ATTN_TILE(KL, VL)                                                     \
  {                                                                           \
    const u16* kl = (KL);                                                     \
    const u16* vl = (VL);                                                     \
    __builtin_amdgcn_s_setprio(1);                                            \
    f32x16 s = __builtin_amdgcn_mfma_f32_32x32x16_bf16(                       \
                 as_bf(*(const uint4*)(kl + lane * 8)), qf[0], zv, 0, 0, 0);  \
    _Pragma("unroll")                                                         \
    for (int c = 1; c < 4; c++)                                               \
      s = __builtin_amdgcn_mfma_f32_32x32x16_bf16(                            \
            as_bf(*(const uint4*)(kl + c * 512 + lane * 8)), qf[c], s, 0, 0, 0); \
    __builtin_amdgcn_s_setprio(0);                                            \
    _Pragma("unroll")                                                         \
    for (int r = 0; r < 16; r++) s[r] = __builtin_amdgcn_exp2f(s[r]);         \
    _Pragma("unroll")                                                         \
    for (int r = 0; r < 16; r += 2) { ls0 += s[r]; ls1 += s[r + 1]; }         \
    bf16x8 pf[2];                                                             \
    _Pragma("unroll")                                                         \
    for (int kc = 0; kc < 2; kc++) {                                          \
      const u32 A0 = pk2(s[8 * kc + 0], s[8 * kc + 1]);                       \
      const u32 A1 = pk2(s[8 * kc + 2], s[8 * kc + 3]);                       \
      const u32 B0 = pk2(s[8 * kc + 4], s[8 * kc + 5]);                       \
      const u32 B1 = pk2(s[8 * kc + 6], s[8 * kc + 7]);                       \
      u32x2 w02 = __builtin_amdgcn_permlane32_swap(A0, B0, false, false);     \
      u32x2 w13 = __builtin_amdgcn_permlane32_swap(A1, B1, false, false);     \
      pf[kc] = as_bf(make_uint4(w02[0], w13[0], w02[1], w13[1]));             \
    }                                                                         \
    __builtin_amdgcn_s_setprio(1);                                            \
    a0 = __builtin_amdgcn_mfma_f32_32x32x16_bf16(                             \
           as_bf(*(const uint4*)(vl + 0    + lane * 8)), pf[0], a0, 0, 0, 0); \
    a1 = __builtin_amdgcn_mfma_f32_32x32x16_bf16(                             \
           as_bf(*(const uint4*)(vl + 512  + lane * 8)), pf[0], a1, 0, 0, 0); \
    a0 = __builtin_amdgcn_mfma_f32_32x32x16_bf16(                             \
           as_bf(*(const uint4*)(vl + 1024 + lane * 8)), pf[1], a0, 0, 0, 0); \
    a1 = __builtin_amdgcn_mfma_f32_32x32x16_bf16(                             \
           as_bf(*(const uint4*)(vl + 1536 + lane * 8)), pf[1], a1, 0, 0, 0); \
    __builtin_amdgcn_s_setprio(0);                                            \
  }

#define ATTN_STEP2(BUF)                                                       \
  ATTN_TILE(pool + (BUF) * 8192,        pool + (BUF) * 8192 + 2048)           \
  ATTN_TILE(pool + (BUF) * 8192 + 4096, pool + (BUF) * 8192 + 6144)

  ASTAGE2(0, 0)
  for (int t = 0; t < 31; ++t) {
    wb0();                              // pair t resident; pair t+1 gets a full
    ASTAGE2(t + 1, (t & 1) ^ 1)         // window of latency cover
    ATTN_STEP2(t & 1)
  }
  wb0();
  ATTN_STEP2(1)                         // pair 31
#undef ATTN_STEP2
#undef ATTN_TILE
#undef ASTAGE2

  __syncthreads();                      // slots dead; reuse pool for epilogue

  float l = ls0 + ls1;
  l += __shfl_xor(l, 32);
  const float inv = 1.f / l;
  u16* ob = pool + (wv * 32) * 72;

#pragma unroll
  for (int r = 0; r < 16; r++) {
    const int dh = (r & 3) + 8 * (r >> 2) + 4 * hi;
    ob[lo * 72 + dh]      = f2b(a0[r] * inv);
    ob[lo * 72 + dh + 32] = f2b(a1[r] * inv);
  }
  __builtin_amdgcn_s_barrier();
  const int qr = lane >> 1, hf = lane & 1;
  const u16* src = ob + qr * 72 + hf * 32;
  const uint4 r0 = *(const uint4*)(src + 0);
  const uint4 r1 = *(const uint4*)(src + 8);
  const uint4 r2 = *(const uint4*)(src + 16);
  const uint4 r3 = *(const uint4*)(src + 24);
  const size_t m = (size_t)b * 2048 + q0 + qr;
  uint4* dst = (uint4*)(O + m * 1024 + (size_t)h * 64 + hf * 32);
  dst[0] = r0; dst[1] = r1; dst[2] = r2; dst[3] = r3;
}

// ---------------------------------------------------------------------------
extern "C" void kernel_launch(void* const* d_in, const int* in_sizes, int n_in,
                              void* d_out, int out_size, void* d_ws, size_t ws_size,
                              hipStream_t stream)
{
  const float* query = (const float*)d_in[0];
  const float* key   = (const float*)d_in[1];
  const float* value = (const float*)d_in[2];
  const float* Wq = (const float*)d_in[3];
  const float* bq = (const float*)d_in[4];
  const float* Wk = (const float*)d_in[5];
  const float* bk = (const float*)d_in[6];
  const float* Wv = (const float*)d_in[7];
  const float* bv = (const float*)d_in[8];
  const float* Wo = (const float*)d_in[9];
  const float* bo = (const float*)d_in[10];

  const size_t MAT = (size_t)8192 * 1024;
  const size_t WMAT = (size_t)1024 * 1024;
  if (ws_size < (6 * MAT + 4 * WMAT) * sizeof(u16)) return;
  u16* Ac3 = (u16*)d_ws;           // 3 bf16 activations (dead after gemm_qkv)
  u16* Wc  = Ac3 + 3 * MAT;        // 4 bf16 weights
  u16* Qw  = Wc + 4 * WMAT;
  u16* Kw  = Qw + MAT;
  u16* Vw  = Kw + MAT;
  u16* Ow  = Ac3;                  // aliases Ac3 (dead by attn time)

  const float qscale = 0.125f * 1.4426950408889634f;  // 1/sqrt(Dh) * log2(e)
  dim3 bl(256, 1, 1);

  hipLaunchKernelGGL(conv_all, dim3(2048, 4), bl, 0, stream,
                     query, key, value, Wq, Wk, Wv, Wo, Ac3, Wc);
  hipLaunchKernelGGL(gemm_qkv, dim3(1536), bl, 0, stream,
                     Ac3, Wc, bq, bk, bv, Qw, Kw, Vw, qscale);
  hipLaunchKernelGGL(attn_k, dim3(1024), bl, 0, stream, Qw, Kw, Vw, Ow);
  hipLaunchKernelGGL(gemm_o, dim3(64, 8), bl, 0, stream,
                     Ow, Wc + 3 * WMAT, bo, (float*)d_out);
}

// Round 17
// 254.150 us; speedup vs baseline: 1.0015x; 1.0015x over previous
//
#include <hip/hip_runtime.h>
#include <hip/hip_bf16.h>

typedef unsigned short u16;
typedef unsigned int u32;
typedef float f32x4 __attribute__((ext_vector_type(4)));
typedef float f32x16 __attribute__((ext_vector_type(16)));
typedef __bf16 bf16x8 __attribute__((ext_vector_type(8)));
typedef u32 u32x2 __attribute__((ext_vector_type(2)));

#define DEV static __device__ __forceinline__

DEV u16 f2b(float f) { __bf16 h = (__bf16)f; u16 r; __builtin_memcpy(&r, &h, 2); return r; }
DEV u32 pk2(float a, float b) { return (u32)f2b(a) | ((u32)f2b(b) << 16); }
DEV bf16x8 as_bf(uint4 v) { bf16x8 r; __builtin_memcpy(&r, &v, 16); return r; }

#define GLDS(g, l) __builtin_amdgcn_global_load_lds( \
    (__attribute__((address_space(1))) void*)(g),     \
    (__attribute__((address_space(3))) void*)(l), 16, 0, 0)

// counted-vmcnt barriers -- PURE global_load_lds streams only.
DEV void wb4() { asm volatile("s_waitcnt vmcnt(4)\n\ts_barrier" ::: "memory"); }
DEV void wb0() { asm volatile("s_waitcnt vmcnt(0)\n\ts_barrier" ::: "memory"); }

// ---------------------------------------------------------------------------
// All fp32->bf16 conversions in one launch. grid (2048, 4):
// y in {0,1,2}: query/key/value (1M x 8 elems, grid-stride x2)
// y == 3: the 4 weight matrices (512K x 8 elems, exactly 1/thread)
// ---------------------------------------------------------------------------
__global__ __launch_bounds__(256) void conv_all(const float* __restrict__ q,
                                                const float* __restrict__ k,
                                                const float* __restrict__ v,
                                                const float* __restrict__ w0,
                                                const float* __restrict__ w1,
                                                const float* __restrict__ w2,
                                                const float* __restrict__ w3,
                                                u16* __restrict__ Ac3,
                                                u16* __restrict__ Wc)
{
  const int y = blockIdx.y;
  if (y < 3) {
    const float* s = y == 0 ? q : (y == 1 ? k : v);
    u16* d = Ac3 + (size_t)y * 8388608;
    const int stride = gridDim.x * 256;
    for (int i = blockIdx.x * 256 + threadIdx.x; i < 1048576; i += stride) {
      const float4* p = (const float4*)(s + (size_t)i * 8);
      const float4 a = p[0], b = p[1];
      *(uint4*)(d + (size_t)i * 8) =
          make_uint4(pk2(a.x, a.y), pk2(a.z, a.w), pk2(b.x, b.y), pk2(b.z, b.w));
    }
  } else {
    const int i = blockIdx.x * 256 + threadIdx.x;     // [0, 524288)
    const int seg = i >> 17, off = i & 131071;
    const float* s = seg == 0 ? w0 : seg == 1 ? w1 : seg == 2 ? w2 : w3;
    const float4* p = (const float4*)(s + (size_t)off * 8);
    const float4 a = p[0], b = p[1];
    *(uint4*)(Wc + (size_t)seg * 1048576 + (size_t)off * 8) =
        make_uint4(pk2(a.x, a.y), pk2(a.z, a.w), pk2(b.x, b.y), pk2(b.z, b.w));
  }
}

// ---------------------------------------------------------------------------
// Fused QKV projection GEMM, z-MAJOR block order: f = z*512 + (m + 64*e).
// Dispatch runs z=0's 512 blocks first, replicating round-7's per-matrix
// locality exactly (A-tile's 8 e-blocks all id=m mod 8 -> same XCD -> A-tile
// L2-hit x8; one z's B (2MB) per XCD at a time), minus 2 launch boundaries.
// 128x128 tile, BK=32, 4 waves 64x64, ring-3 + counted vmcnt(4) (proven).
// ---------------------------------------------------------------------------
__global__ __launch_bounds__(256) void gemm_qkv(const u16* __restrict__ Ac,
                                                const u16* __restrict__ Wc,
                                                const float* __restrict__ b0,
                                                const float* __restrict__ b1,
                                                const float* __restrict__ b2,
                                                u16* __restrict__ C0,
                                                u16* __restrict__ C1,
                                                u16* __restrict__ C2,
                                                float qscale)
{
  __shared__ u16 lds[3][8192];                 // ring slot: [A 4096 | B 4096]
  const int tid = threadIdx.x;
  const int lane = tid & 63, w = tid >> 6;
  const int f = blockIdx.x;
  const int z = f >> 9, r = f & 511;
  const int m0 = (r & 63) * 128, e0 = (r >> 6) * 128;
  const int wrb = (w >> 1) * 4, wcb = (w & 1) * 4;

  const u16* A = Ac + (size_t)z * 8388608;
  const u16* Wp = Wc + (size_t)z * 1048576;
  const float* bias = z == 0 ? b0 : (z == 1 ? b1 : b2);
  u16* Cp = z == 0 ? C0 : (z == 1 ? C1 : C2);
  const float scale = (z == 0) ? qscale : 1.0f;
  const int cmode = (z == 2) ? 3 : 2;

  f32x4 acc[4][4];
#pragma unroll
  for (int ii = 0; ii < 4; ii++)
#pragma unroll
    for (int j = 0; j < 4; j++)
#pragma unroll
      for (int rr = 0; rr < 4; rr++) acc[ii][j][rr] = 0.f;

  const u16* gA = A  + (size_t)(m0 + w * 32 + (lane & 15)) * 1024 + (lane >> 4) * 8;
  const u16* gB = Wp + (size_t)(e0 + w * 32 + (lane & 15)) * 1024 + (lane >> 4) * 8;

#define GSTAGE(K0, BUF)                                        \
  GLDS(gA + (K0),         &lds[BUF][w * 1024]);                \
  GLDS(gA + (K0) + 16384, &lds[BUF][w * 1024 + 512]);          \
  GLDS(gB + (K0),         &lds[BUF][4096 + w * 1024]);         \
  GLDS(gB + (K0) + 16384, &lds[BUF][4096 + w * 1024 + 512]);

  GSTAGE(0, 0)
  GSTAGE(32, 1)

  const int fo = (lane >> 4) * 128 + (lane & 15) * 8;

#define GEMM_STEP(BUF)                                                         \
  {                                                                            \
    const u16* la = &lds[BUF][0];                                              \
    const u16* lb = &lds[BUF][4096];                                           \
    bf16x8 af[4], bfr[4];                                                      \
    _Pragma("unroll")                                                          \
    for (int ii = 0; ii < 4; ii++) {                                           \
      af[ii]  = as_bf(*(const uint4*)(la + (wrb + ii) * 512 + fo));            \
      bfr[ii] = as_bf(*(const uint4*)(lb + (wcb + ii) * 512 + fo));            \
    }                                                                          \
    _Pragma("unroll")                                                          \
    for (int ii = 0; ii < 4; ii++)                                             \
      _Pragma("unroll")                                                        \
      for (int j = 0; j < 4; j++)                                              \
        acc[ii][j] = __builtin_amdgcn_mfma_f32_16x16x32_bf16(af[ii], bfr[j],   \
                                                             acc[ii][j], 0, 0, 0); \
  }

  for (int t = 0; t < 30; t += 3) {
    wb4(); GSTAGE((t + 2) * 32, 2) GEMM_STEP(0)
    wb4(); GSTAGE((t + 3) * 32, 0) GEMM_STEP(1)
    wb4(); GSTAGE((t + 4) * 32, 1) GEMM_STEP(2)
  }
  wb4(); GEMM_STEP(0)
  wb0(); GEMM_STEP(1)
#undef GEMM_STEP
#undef GSTAGE

  const int col = lane & 15, rb4 = (lane >> 4) * 4;
  const int wr = wrb * 16, wc = wcb * 16;
#pragma unroll
  for (int j = 0; j < 4; j++) {
    const int e = e0 + wc + j * 16 + col;
    const float bv2 = bias[e];
#pragma unroll
    for (int ii = 0; ii < 4; ii++) {
#pragma unroll
      for (int rr = 0; rr < 4; rr++) {
        const int m = m0 + wr + ii * 16 + rb4 + rr;
        const float v = (acc[ii][j][rr] + bv2) * scale;
        const int b = m >> 11, s = m & 2047, h = e >> 6, dh = e & 63;
        const size_t bh = (size_t)(b * 16 + h);
        if (cmode == 2) {
          const size_t idx = (((bh * 64 + (s >> 5)) * 4 + (dh >> 4)) * 64
                              + ((dh >> 3) & 1) * 32 + (s & 31)) * 8 + (dh & 7);
          Cp[idx] = f2b(v);
        } else {
          const size_t idx = ((bh * 64 + (s >> 5)) * 8 + ((s >> 4) & 1) * 4
                              + (dh >> 5) * 2 + ((s >> 3) & 1)) * 256
                             + (size_t)(dh & 31) * 8 + (s & 7);
          Cp[idx] = f2b(v);
        }
      }
    }
  }
}

// ---------------------------------------------------------------------------
// Output GEMM (proven): bf16 A/W via GLDS, fp32 out + bias. 128x128, BK=32,
// 4 waves, ring-3 + counted vmcnt(4).
// ---------------------------------------------------------------------------
__global__ __launch_bounds__(256) void gemm_o(const u16* __restrict__ A,
                                              const u16* __restrict__ W,
                                              const float* __restrict__ bias,
                                              float* __restrict__ Cp)
{
  __shared__ u16 lds[3][8192];
  const int tid = threadIdx.x;
  const int lane = tid & 63, w = tid >> 6;
  const int m0 = blockIdx.x * 128, e0 = blockIdx.y * 128;
  const int wrb = (w >> 1) * 4, wcb = (w & 1) * 4;

  f32x4 acc[4][4];
#pragma unroll
  for (int i = 0; i < 4; i++)
#pragma unroll
    for (int j = 0; j < 4; j++)
#pragma unroll
      for (int r = 0; r < 4; r++) acc[i][j][r] = 0.f;

  const u16* gA = A + (size_t)(m0 + w * 32 + (lane & 15)) * 1024 + (lane >> 4) * 8;
  const u16* gB = W + (size_t)(e0 + w * 32 + (lane & 15)) * 1024 + (lane >> 4) * 8;

#define GSTAGE(K0, BUF)                                        \
  GLDS(gA + (K0),         &lds[BUF][w * 1024]);                \
  GLDS(gA + (K0) + 16384, &lds[BUF][w * 1024 + 512]);          \
  GLDS(gB + (K0),         &lds[BUF][4096 + w * 1024]);         \
  GLDS(gB + (K0) + 16384, &lds[BUF][4096 + w * 1024 + 512]);

  GSTAGE(0, 0)
  GSTAGE(32, 1)

  const int fo = (lane >> 4) * 128 + (lane & 15) * 8;

#define GEMM_STEP(BUF)                                                         \
  {                                                                            \
    const u16* la = &lds[BUF][0];                                              \
    const u16* lb = &lds[BUF][4096];                                           \
    bf16x8 af[4], bfr[4];                                                      \
    _Pragma("unroll")                                                          \
    for (int i = 0; i < 4; i++) {                                              \
      af[i]  = as_bf(*(const uint4*)(la + (wrb + i) * 512 + fo));              \
      bfr[i] = as_bf(*(const uint4*)(lb + (wcb + i) * 512 + fo));              \
    }                                                                          \
    _Pragma("unroll")                                                          \
    for (int i = 0; i < 4; i++)                                                \
      _Pragma("unroll")                                                        \
      for (int j = 0; j < 4; j++)                                              \
        acc[i][j] = __builtin_amdgcn_mfma_f32_16x16x32_bf16(af[i], bfr[j],     \
                                                            acc[i][j], 0, 0, 0); \
  }

  for (int t = 0; t < 30; t += 3) {
    wb4(); GSTAGE((t + 2) * 32, 2) GEMM_STEP(0)
    wb4(); GSTAGE((t + 3) * 32, 0) GEMM_STEP(1)
    wb4(); GSTAGE((t + 4) * 32, 1) GEMM_STEP(2)
  }
  wb4(); GEMM_STEP(0)
  wb0(); GEMM_STEP(1)
#undef GEMM_STEP
#undef GSTAGE

  const int col = lane & 15, rb4 = (lane >> 4) * 4;
  const int wr = wrb * 16, wc = wcb * 16;
#pragma unroll
  for (int j = 0; j < 4; j++) {
    const int e = e0 + wc + j * 16 + col;
    const float bv = bias[e];
#pragma unroll
    for (int i = 0; i < 4; i++) {
#pragma unroll
      for (int r = 0; r < 4; r++) {
        const int m = m0 + wr + i * 16 + rb4 + r;
        Cp[(size_t)m * 1024 + e] = acc[i][j][r] + bv;
      }
    }
  }
}

// ---------------------------------------------------------------------------
// Flash attention v9: 2 k-tiles per barrier window. 4 waves x 32 q = 128 q of
// one bh; double-buffered 16KB slots [KA|VA|KB|VB], 32 barriers (was 64), two
// independent QK/softmax/PV chains per window for ILP (diagnosis: latency-
// bound, both pipes <50%). Fixed-shift softmax p=exp2(s); raw v_exp_f32;
// VALU denominator; XCD-grouped bh mapping.
// ---------------------------------------------------------------------------
__global__ __launch_bounds__(256, 4) void attn_k(const u16* __restrict__ Qb,
                                                 const u16* __restrict__ Kb,
                                                 const u16* __restrict__ Vb,
                                                 u16* __restrict__ O)
{
  __shared__ u16 pool[16384];      // dbuf 2 x 8192; epilogue aliases
  const int tid = threadIdx.x, wv = tid >> 6, lane = tid & 63;
  const int lo = lane & 31, hi = lane >> 5;
  const int bid = blockIdx.x;
  const int xcd = bid & 7, ix = bid >> 3;
  const int bh = xcd * 8 + (ix & 7);
  const int qb = (ix >> 3) * 4 + wv;
  const int b = bh >> 4, h = bh & 15, q0 = qb * 32;

  const u16* qp = Qb + ((size_t)(bh * 64 + qb) * 4) * 512 + (size_t)lane * 8;
  bf16x8 qf[4];
#pragma unroll
  for (int c = 0; c < 4; c++) qf[c] = as_bf(*(const uint4*)(qp + c * 512));

  f32x16 a0, a1, zv;
#pragma unroll
  for (int r = 0; r < 16; r++) { a0[r] = 0.f; a1[r] = 0.f; zv[r] = 0.f; }
  float ls0 = 0.f, ls1 = 0.f;

  const u16* sgK = Kb + (size_t)bh * 131072 + wv * 512 + (size_t)lane * 8;
  const u16* sgV = Vb + (size_t)bh * 131072 + wv * 512 + (size_t)lane * 8;

// stage tile-pair T2 (tiles 2*T2, 2*T2+1) into slot BUF
#define ASTAGE2(T2, BUF)                                                       \
  GLDS(sgK + (size_t)(2 * (T2))     * 2048, pool + (BUF) * 8192 +        wv * 512); \
  GLDS(sgV + (size_t)(2 * (T2))     * 2048, pool + (BUF) * 8192 + 2048 + wv * 512); \
  GLDS(sgK + (size_t)(2 * (T2) + 1) * 2048, pool + (BUF) * 8192 + 4096 + wv * 512); \
  GLDS(sgV + (size_t)(2 * (T2) + 1) * 2048, pool + (BUF) * 8192 + 6144 + wv * 512);

#define ATTN_TILE(KL, VL)                                                     \
  {                                                                           \
    const u16* kl = (KL);                                                     \
    const u16* vl = (VL);                                                     \
    __builtin_amdgcn_s_setprio(1);                                            \
    f32x16 s = __builtin_amdgcn_mfma_f32_32x32x16_bf16(                       \
                 as_bf(*(const uint4*)(kl + lane * 8)), qf[0], zv, 0, 0, 0);  \
    _Pragma("unroll")                                                         \
    for (int c = 1; c < 4; c++)                                               \
      s = __builtin_amdgcn_mfma_f32_32x32x16_bf16(                            \
            as_bf(*(const uint4*)(kl + c * 512 + lane * 8)), qf[c], s, 0, 0, 0); \
    __builtin_amdgcn_s_setprio(0);                                            \
    _Pragma("unroll")                                                         \
    for (int r = 0; r < 16; r++) s[r] = __builtin_amdgcn_exp2f(s[r]);         \
    _Pragma("unroll")                                                         \
    for (int r = 0; r < 16; r += 2) { ls0 += s[r]; ls1 += s[r + 1]; }         \
    bf16x8 pf[2];                                                             \
    _Pragma("unroll")                                                         \
    for (int kc = 0; kc < 2; kc++) {                                          \
      const u32 A0 = pk2(s[8 * kc + 0], s[8 * kc + 1]);                       \
      const u32 A1 = pk2(s[8 * kc + 2], s[8 * kc + 3]);                       \
      const u32 B0 = pk2(s[8 * kc + 4], s[8 * kc + 5]);                       \
      const u32 B1 = pk2(s[8 * kc + 6], s[8 * kc + 7]);                       \
      u32x2 w02 = __builtin_amdgcn_permlane32_swap(A0, B0, false, false);     \
      u32x2 w13 = __builtin_amdgcn_permlane32_swap(A1, B1, false, false);     \
      pf[kc] = as_bf(make_uint4(w02[0], w13[0], w02[1], w13[1]));             \
    }                                                                         \
    __builtin_amdgcn_s_setprio(1);                                            \
    a0 = __builtin_amdgcn_mfma_f32_32x32x16_bf16(                             \
           as_bf(*(const uint4*)(vl + 0    + lane * 8)), pf[0], a0, 0, 0, 0); \
    a1 = __builtin_amdgcn_mfma_f32_32x32x16_bf16(                             \
           as_bf(*(const uint4*)(vl + 512  + lane * 8)), pf[0], a1, 0, 0, 0); \
    a0 = __builtin_amdgcn_mfma_f32_32x32x16_bf16(                             \
           as_bf(*(const uint4*)(vl + 1024 + lane * 8)), pf[1], a0, 0, 0, 0); \
    a1 = __builtin_amdgcn_mfma_f32_32x32x16_bf16(                             \
           as_bf(*(const uint4*)(vl + 1536 + lane * 8)), pf[1], a1, 0, 0, 0); \
    __builtin_amdgcn_s_setprio(0);                                            \
  }

#define ATTN_STEP2(BUF)                                                       \
  ATTN_TILE(pool + (BUF) * 8192,        pool + (BUF) * 8192 + 2048)           \
  ATTN_TILE(pool + (BUF) * 8192 + 4096, pool + (BUF) * 8192 + 6144)

  ASTAGE2(0, 0)
  for (int t = 0; t < 31; ++t) {
    wb0();                              // pair t resident; pair t+1 gets a full
    ASTAGE2(t + 1, (t & 1) ^ 1)         // window of latency cover
    ATTN_STEP2(t & 1)
  }
  wb0();
  ATTN_STEP2(1)                         // pair 31
#undef ATTN_STEP2
#undef ATTN_TILE
#undef ASTAGE2

  __syncthreads();                      // slots dead; reuse pool for epilogue

  float l = ls0 + ls1;
  l += __shfl_xor(l, 32);
  const float inv = 1.f / l;
  u16* ob = pool + (wv * 32) * 72;

#pragma unroll
  for (int r = 0; r < 16; r++) {
    const int dh = (r & 3) + 8 * (r >> 2) + 4 * hi;
    ob[lo * 72 + dh]      = f2b(a0[r] * inv);
    ob[lo * 72 + dh + 32] = f2b(a1[r] * inv);
  }
  __builtin_amdgcn_s_barrier();
  const int qr = lane >> 1, hf = lane & 1;
  const u16* src = ob + qr * 72 + hf * 32;
  const uint4 r0 = *(const uint4*)(src + 0);
  const uint4 r1 = *(const uint4*)(src + 8);
  const uint4 r2 = *(const uint4*)(src + 16);
  const uint4 r3 = *(const uint4*)(src + 24);
  const size_t m = (size_t)b * 2048 + q0 + qr;
  uint4* dst = (uint4*)(O + m * 1024 + (size_t)h * 64 + hf * 32);
  dst[0] = r0; dst[1] = r1; dst[2] = r2; dst[3] = r3;
}

// ---------------------------------------------------------------------------
extern "C" void kernel_launch(void* const* d_in, const int* in_sizes, int n_in,
                              void* d_out, int out_size, void* d_ws, size_t ws_size,
                              hipStream_t stream)
{
  const float* query = (const float*)d_in[0];
  const float* key   = (const float*)d_in[1];
  const float* value = (const float*)d_in[2];
  const float* Wq = (const float*)d_in[3];
  const float* bq = (const float*)d_in[4];
  const float* Wk = (const float*)d_in[5];
  const float* bk = (const float*)d_in[6];
  const float* Wv = (const float*)d_in[7];
  const float* bv = (const float*)d_in[8];
  const float* Wo = (const float*)d_in[9];
  const float* bo = (const float*)d_in[10];

  const size_t MAT = (size_t)8192 * 1024;
  const size_t WMAT = (size_t)1024 * 1024;
  if (ws_size < (6 * MAT + 4 * WMAT) * sizeof(u16)) return;
  u16* Ac3 = (u16*)d_ws;           // 3 bf16 activations (dead after gemm_qkv)
  u16* Wc  = Ac3 + 3 * MAT;        // 4 bf16 weights
  u16* Qw  = Wc + 4 * WMAT;
  u16* Kw  = Qw + MAT;
  u16* Vw  = Kw + MAT;
  u16* Ow  = Ac3;                  // aliases Ac3 (dead by attn time)

  const float qscale = 0.125f * 1.4426950408889634f;  // 1/sqrt(Dh) * log2(e)
  dim3 bl(256, 1, 1);

  hipLaunchKernelGGL(conv_all, dim3(2048, 4), bl, 0, stream,
                     query, key, value, Wq, Wk, Wv, Wo, Ac3, Wc);
  hipLaunchKernelGGL(gemm_qkv, dim3(1536), bl, 0, stream,
                     Ac3, Wc, bq, bk, bv, Qw, Kw, Vw, qscale);
  hipLaunchKernelGGL(attn_k, dim3(1024), bl, 0, stream, Qw, Kw, Vw, Ow);
  hipLaunchKernelGGL(gemm_o, dim3(64, 8), bl, 0, stream,
                     Ow, Wc + 3 * WMAT, bo, (float*)d_out);
}